// Round 2
// baseline (321.549 us; speedup 1.0000x reference)
//
#include <hip/hip_runtime.h>

// FSUConv2d stochastic-computing conv. N=8,C=32,H=W=16,OC=64,K=3,PAD=1,RLEN=256.
// CKK=288, B=2048. HBM-dominant data: wrdx_i1/wrdx_i0 [2048,64,288] i32 = 302 MB.
//
// Math: out[b,o] = sum_k [ x_k ? (w>rng[i1]) : (w<=rng[i0]) ] + (b_bin>rng[brdx])
// rng[i] = bitreverse8(i) (van der Corput) -> computed via v_bfrev_b32.
// Trick: x=0 case (w<=t0) <=> (255-t0) <= (255-w) <=> brev(~i0)>>24 <= 255-w.
// So per element: I = x? i1 : ~i0 ; W' = x? w-1 : 255-w ; bit = (brev(I)>>24 <= W') signed.
// Edge cases w=0 (W'=-1, never) and w=256 (W'=255, always) are exact under signed cmp.

#define CH   32
#define HH   16
#define WW   16
#define OCN  64
#define CKK  288
#define LL   256
#define BB   2048

// ---------------- kernel 1: prep (x unfold -> masks, w -> int tables) -------
__global__ __launch_bounds__(256) void prep_kernel(
    const float* __restrict__ x,      // [8,32,16,16]
    const float* __restrict__ w_bin,  // [64,288]
    int* __restrict__ xm,             // [2048,288]  0 / -1
    int* __restrict__ w1m,            // [64,288]    (int)w - 1
    int* __restrict__ w0c)            // [64,288]    255 - (int)w
{
    int e = blockIdx.x * 256 + threadIdx.x;
    if (e < BB * CKK) {
        int b = e / CKK, k = e - b * CKK;
        int c = k / 9,  r = k - c * 9;
        int kh = r / 3, kw = r - kh * 3;
        int n = b >> 8, l = b & 255, h = l >> 4, w0 = l & 15;
        int ih = h + kh - 1, iw = w0 + kw - 1;
        float v = 0.f;
        if ((unsigned)ih < 16u && (unsigned)iw < 16u)
            v = x[((n * CH + c) * HH + ih) * WW + iw];
        xm[e] = (v != 0.f) ? -1 : 0;
    } else {
        int e2 = e - BB * CKK;
        if (e2 < OCN * CKK) {
            int wi = (int)w_bin[e2];   // integer-valued float, exact trunc
            w1m[e2] = wi - 1;
            w0c[e2] = 255 - wi;
        }
    }
}

// ---------------- kernel 2: main stream ------------------------------------
__device__ __forceinline__ int elem(int i1, int i0, int m, int u, int v) {
    int ni0 = ~i0;
    int I  = ni0 ^ ((i1 ^ ni0) & m);   // m ? i1  : ~i0   (v_bfi)
    int Wp = v   ^ ((u  ^ v)  & m);    // m ? w-1 : 255-w (v_bfi)
    int t  = (int)(__brev((unsigned)I) >> 24);
    return (t <= Wp) ? 1 : 0;
}

__global__ __launch_bounds__(256, 4) void fsu_main(
    const int*   __restrict__ wrdx1,  // [2048,64,288]
    const int*   __restrict__ wrdx0,  // [2048,64,288]
    const int*   __restrict__ xm,     // [2048,288]
    const int*   __restrict__ w1m,    // [64,288]
    const int*   __restrict__ w0c,    // [64,288]
    const float* __restrict__ b_bin,  // [64]
    const int*   __restrict__ brdx,   // [64]
    float*       __restrict__ out)    // [8,64,16,16]
{
    // wave = (b, og); group g = lane>>3 -> o = og*8+g; lane j = lane&7 owns
    // int4 chunks j, j+8, ..., j+64 (72 chunks = 288 ints per row, exact).
    const int wid  = (blockIdx.x << 2) + (threadIdx.x >> 6);
    const int lane = threadIdx.x & 63;
    const int b    = wid >> 3;
    const int og   = wid & 7;
    const int g    = lane >> 3;
    const int j    = lane & 7;
    const int o    = (og << 3) + g;

    const int4* r1 = (const int4*)(wrdx1 + ((size_t)b * OCN + o) * CKK);
    const int4* r0 = (const int4*)(wrdx0 + ((size_t)b * OCN + o) * CKK);
    const int4* xr = (const int4*)(xm  + (size_t)b * CKK);
    const int4* wa = (const int4*)(w1m + (size_t)o * CKK);
    const int4* wb = (const int4*)(w0c + (size_t)o * CKK);

    // Prefetch the entire HBM stream for this wave (18 x 16B per lane in flight).
    int4 A1[9], A0[9];
#pragma unroll
    for (int t = 0; t < 9; ++t) {
        A1[t] = r1[j + (t << 3)];
        A0[t] = r0[j + (t << 3)];
    }

    int cnt = 0;
#pragma unroll
    for (int t = 0; t < 9; ++t) {
        const int c = j + (t << 3);
        int4 m = xr[c];   // L1/L2 hit (broadcast across the 8 groups)
        int4 u = wa[c];   // L1/L2 hit (72 KB table)
        int4 v = wb[c];
        cnt += elem(A1[t].x, A0[t].x, m.x, u.x, v.x);
        cnt += elem(A1[t].y, A0[t].y, m.y, u.y, v.y);
        cnt += elem(A1[t].z, A0[t].z, m.z, u.z, v.z);
        cnt += elem(A1[t].w, A0[t].w, m.w, u.w, v.w);
    }

    // reduce across the 8 lanes of this group (j = 0 collects)
    cnt += __shfl_down(cnt, 4);
    cnt += __shfl_down(cnt, 2);
    cnt += __shfl_down(cnt, 1);

    if (j == 0) {
        int n = b >> 8, l = b & 255;
        float bb = (b_bin[o] > (float)(__brev((unsigned)brdx[o]) >> 24)) ? 1.f : 0.f;
        out[((size_t)n * OCN + o) * LL + l] = (float)cnt + bb;
    }
}

extern "C" void kernel_launch(void* const* d_in, const int* in_sizes, int n_in,
                              void* d_out, int out_size, void* d_ws, size_t ws_size,
                              hipStream_t stream) {
    const float* x     = (const float*)d_in[0];
    const float* w_bin = (const float*)d_in[1];
    const float* b_bin = (const float*)d_in[2];
    // d_in[3] = rng — closed-form bit-reversal
    const int*   wrdx1 = (const int*)d_in[4];
    const int*   wrdx0 = (const int*)d_in[5];
    const int*   brdx  = (const int*)d_in[6];
    float*       out   = (float*)d_out;

    int* xm  = (int*)d_ws;            // 2048*288*4 = 2.25 MB
    int* w1m = xm  + BB * CKK;        // 72 KB
    int* w0c = w1m + OCN * CKK;       // 72 KB  (total ~2.4 MB of ws)

    {   // prep: BB*CKK + OCN*CKK elements, one thread each
        int total = BB * CKK + OCN * CKK;
        dim3 grid((total + 255) / 256), block(256);
        prep_kernel<<<grid, block, 0, stream>>>(x, w_bin, xm, w1m, w0c);
    }
    {   // main: 2048*8 waves, 4 waves/block
        dim3 grid(BB * 8 / 4), block(256);
        fsu_main<<<grid, block, 0, stream>>>(wrdx1, wrdx0, xm, w1m, w0c,
                                             b_bin, brdx, out);
    }
}

// Round 3
// 320.684 us; speedup vs baseline: 1.0027x; 1.0027x over previous
//
#include <hip/hip_runtime.h>

// FSUConv2d stochastic-computing conv. N=8,C=32,H=W=16,OC=64,K=3,PAD=1,RLEN=256.
// CKK=288, B=2048. HBM-dominant data: wrdx_i1/wrdx_i0 [2048,64,288] i32 = 302 MB.
//
// Math: out[b,o] = sum_k [ x_k ? (w>rng[i1]) : (w<=rng[i0]) ] + (b_bin>rng[brdx])
// rng[i] = bitreverse8(i) (van der Corput) -> computed via v_bfrev_b32.
// Per element: I = x? i1 : ~i0 ; W' = x? w-1 : 255-w ; bit = (brev(I)>>24 <= W') signed.
//
// R2: force 18x int4 prefetch to stay in registers (launch_bounds(256,2) +
// sched_barrier) — R1's VGPR_Count=44 proved the compiler sank the prefetch,
// leaving ~2-5 outstanding loads/wave -> latency-bound at 2.7 TB/s combined.

#define CH   32
#define HH   16
#define WW   16
#define OCN  64
#define CKK  288
#define LL   256
#define BB   2048

// ---------------- kernel 1: prep (x unfold -> masks, w -> int tables) -------
__global__ __launch_bounds__(256) void prep_kernel(
    const float* __restrict__ x,      // [8,32,16,16]
    const float* __restrict__ w_bin,  // [64,288]
    int* __restrict__ xm,             // [2048,288]  0 / -1
    int* __restrict__ w1m,            // [64,288]    (int)w - 1
    int* __restrict__ w0c)            // [64,288]    255 - (int)w
{
    int e = blockIdx.x * 256 + threadIdx.x;
    if (e < BB * CKK) {
        int b = e / CKK, k = e - b * CKK;
        int c = k / 9,  r = k - c * 9;
        int kh = r / 3, kw = r - kh * 3;
        int n = b >> 8, l = b & 255, h = l >> 4, w0 = l & 15;
        int ih = h + kh - 1, iw = w0 + kw - 1;
        float v = 0.f;
        if ((unsigned)ih < 16u && (unsigned)iw < 16u)
            v = x[((n * CH + c) * HH + ih) * WW + iw];
        xm[e] = (v != 0.f) ? -1 : 0;
    } else {
        int e2 = e - BB * CKK;
        if (e2 < OCN * CKK) {
            int wi = (int)w_bin[e2];   // integer-valued float, exact trunc
            w1m[e2] = wi - 1;
            w0c[e2] = 255 - wi;
        }
    }
}

// ---------------- kernel 2: main stream ------------------------------------
__device__ __forceinline__ int elem(int i1, int i0, int m, int u, int v) {
    int ni0 = ~i0;
    int I  = ni0 ^ ((i1 ^ ni0) & m);   // m ? i1  : ~i0   (v_bfi)
    int Wp = v   ^ ((u  ^ v)  & m);    // m ? w-1 : 255-w (v_bfi)
    int t  = (int)(__brev((unsigned)I) >> 24);
    return (t <= Wp) ? 1 : 0;
}

__global__ __launch_bounds__(256, 2) void fsu_main(
    const int*   __restrict__ wrdx1,  // [2048,64,288]
    const int*   __restrict__ wrdx0,  // [2048,64,288]
    const int*   __restrict__ xm,     // [2048,288]
    const int*   __restrict__ w1m,    // [64,288]
    const int*   __restrict__ w0c,    // [64,288]
    const float* __restrict__ b_bin,  // [64]
    const int*   __restrict__ brdx,   // [64]
    float*       __restrict__ out)    // [8,64,16,16]
{
    // wave = (b, og); group g = lane>>3 -> o = og*8+g; lane j = lane&7 owns
    // int4 chunks j, j+8, ..., j+64 (72 chunks = 288 ints per row, exact).
    const int wid  = (blockIdx.x << 2) + (threadIdx.x >> 6);
    const int lane = threadIdx.x & 63;
    const int b    = wid >> 3;
    const int og   = wid & 7;
    const int g    = lane >> 3;
    const int j    = lane & 7;
    const int o    = (og << 3) + g;

    const int4* r1 = (const int4*)(wrdx1 + ((size_t)b * OCN + o) * CKK);
    const int4* r0 = (const int4*)(wrdx0 + ((size_t)b * OCN + o) * CKK);
    const int4* xr = (const int4*)(xm  + (size_t)b * CKK);
    const int4* wa = (const int4*)(w1m + (size_t)o * CKK);
    const int4* wb = (const int4*)(w0c + (size_t)o * CKK);

    // Prefetch the ENTIRE HBM stream for this wave: 18 x 16B/lane = 18 KB/wave
    // in flight. launch_bounds(256,2) gives the allocator room (<=256 VGPR) so
    // these 72 load-result VGPRs stay live; sched_barrier(0) forbids sinking.
    int4 A1[9], A0[9];
#pragma unroll
    for (int t = 0; t < 9; ++t) {
        A1[t] = r1[j + (t << 3)];
        A0[t] = r0[j + (t << 3)];
    }
    __builtin_amdgcn_sched_barrier(0);

    int cnt = 0;
#pragma unroll
    for (int t = 0; t < 9; ++t) {
        const int c = j + (t << 3);
        int4 m = xr[c];   // L1/L2 hit (shared across the 8 o-groups)
        int4 u = wa[c];   // L1/L2 hit (72 KB table, grid-wide reuse)
        int4 v = wb[c];
        cnt += elem(A1[t].x, A0[t].x, m.x, u.x, v.x);
        cnt += elem(A1[t].y, A0[t].y, m.y, u.y, v.y);
        cnt += elem(A1[t].z, A0[t].z, m.z, u.z, v.z);
        cnt += elem(A1[t].w, A0[t].w, m.w, u.w, v.w);
    }

    // reduce across the 8 lanes of this group (j = 0 collects)
    cnt += __shfl_down(cnt, 4);
    cnt += __shfl_down(cnt, 2);
    cnt += __shfl_down(cnt, 1);

    if (j == 0) {
        int n = b >> 8, l = b & 255;
        float bb = (b_bin[o] > (float)(__brev((unsigned)brdx[o]) >> 24)) ? 1.f : 0.f;
        out[((size_t)n * OCN + o) * LL + l] = (float)cnt + bb;
    }
}

extern "C" void kernel_launch(void* const* d_in, const int* in_sizes, int n_in,
                              void* d_out, int out_size, void* d_ws, size_t ws_size,
                              hipStream_t stream) {
    const float* x     = (const float*)d_in[0];
    const float* w_bin = (const float*)d_in[1];
    const float* b_bin = (const float*)d_in[2];
    // d_in[3] = rng — closed-form bit-reversal
    const int*   wrdx1 = (const int*)d_in[4];
    const int*   wrdx0 = (const int*)d_in[5];
    const int*   brdx  = (const int*)d_in[6];
    float*       out   = (float*)d_out;

    int* xm  = (int*)d_ws;            // 2048*288*4 = 2.25 MB
    int* w1m = xm  + BB * CKK;        // 72 KB
    int* w0c = w1m + OCN * CKK;       // 72 KB  (total ~2.4 MB of ws)

    {   // prep: BB*CKK + OCN*CKK elements, one thread each
        int total = BB * CKK + OCN * CKK;
        dim3 grid((total + 255) / 256), block(256);
        prep_kernel<<<grid, block, 0, stream>>>(x, w_bin, xm, w1m, w0c);
    }
    {   // main: 2048*8 waves, 4 waves/block
        dim3 grid(BB * 8 / 4), block(256);
        fsu_main<<<grid, block, 0, stream>>>(wrdx1, wrdx0, xm, w1m, w0c,
                                             b_bin, brdx, out);
    }
}